// Round 15
// baseline (133.856 us; speedup 1.0000x reference)
//
#include <hip/hip_runtime.h>
#include <math.h>

#define NFFT 1024
#define NF   513   // NFFT/2 + 1
#define NSL  8     // accumulator slices (contention spread)
#define SLW  520   // PSD slice stride (floats)

typedef unsigned uint2v __attribute__((ext_vector_type(2)));
typedef float f32x2 __attribute__((ext_vector_type(2)));

__device__ __forceinline__ f32x2 tov(float2 a){ f32x2 r; r[0]=a.x; r[1]=a.y; return r; }
__device__ __forceinline__ float2 tof(f32x2 a){ return make_float2(a[0], a[1]); }

// ---- packed fp32 complex helpers (VOP3P) — R11/R12-validated ----
__device__ __forceinline__ float2 pk_cmul(float2 af, float2 bf){
    f32x2 a = tov(af), b = tov(bf), t, d;
    asm("v_pk_mul_f32 %0, %1, %2 op_sel:[0,0] op_sel_hi:[0,1]"
        : "=v"(t) : "v"(a), "v"(b));                       // {ax*bx, ax*by}
    asm("v_pk_fma_f32 %0, %1, %2, %3 op_sel:[1,1,0] op_sel_hi:[1,0,1] neg_lo:[1,0,0]"
        : "=v"(d) : "v"(a), "v"(b), "v"(t));               // {-ay*by+t.lo, ay*bx+t.hi}
    return tof(d);
}
__device__ __forceinline__ float2 pk_add(float2 af, float2 bf){
    f32x2 a = tov(af), b = tov(bf), d;
    asm("v_pk_add_f32 %0, %1, %2" : "=v"(d) : "v"(a), "v"(b));
    return tof(d);
}
__device__ __forceinline__ float2 pk_sub(float2 af, float2 bf){
    f32x2 a = tov(af), b = tov(bf), d;
    asm("v_pk_add_f32 %0, %1, %2 neg_lo:[0,1] neg_hi:[0,1]" : "=v"(d) : "v"(a), "v"(b));
    return tof(d);
}
__device__ __forceinline__ float2 pk_fma_s(float2 af, float2 sf, float2 cf){
    f32x2 a = tov(af), s = tov(sf), c = tov(cf), d;
    asm("v_pk_fma_f32 %0, %1, %2, %3" : "=v"(d) : "v"(a), "v"(s), "v"(c));
    return tof(d);
}

__device__ __forceinline__ float2 shflxor2(float2 v, int m){
    return make_float2(__shfl_xor(v.x, m), __shfl_xor(v.y, m));
}
__device__ __forceinline__ float2 shflidx2(float2 v, int idx){
    return make_float2(__shfl(v.x, idx), __shfl(v.y, idx));
}
__device__ __forceinline__ int brev6(int x){ return (int)(__brev((unsigned)x) >> 26); }

// DPP quad_perm: xor1 = [1,0,3,2] = 0xB1, xor2 = [2,3,0,1] = 0x4E
template<int CTRL>
__device__ __forceinline__ float2 dppqp2(float2 v){
    int x = __builtin_amdgcn_update_dpp(0, __float_as_int(v.x), CTRL, 0xf, 0xf, true);
    int y = __builtin_amdgcn_update_dpp(0, __float_as_int(v.y), CTRL, 0xf, 0xf, true);
    return make_float2(__int_as_float(x), __int_as_float(y));
}

// xor-partner within 16-lane row via two masked DPP shifts (VALU pipe, no DS).
template<int CSHL, int CSHR, int BM_SHL, int BM_SHR>
__device__ __forceinline__ float xorshift(float z){
    int t = __builtin_amdgcn_update_dpp(0, __float_as_int(z), CSHL, 0xF, BM_SHL, true);
    t     = __builtin_amdgcn_update_dpp(t, __float_as_int(z), CSHR, 0xF, BM_SHR, false);
    return __int_as_float(t);
}
__device__ __forceinline__ float xp4(float z){ return xorshift<0x104, 0x114, 0x5, 0xA>(z); }
__device__ __forceinline__ float xp8(float z){ return xorshift<0x108, 0x118, 0x3, 0xC>(z); }

// butterfly input pair (P, Q): inner = P + sg*Q  (validated convention)
struct f2pair { float2 P, Q; };

template<int S>
__device__ __forceinline__ f2pair part(float2 z){
    if constexpr (S == 0) {
#if __has_builtin(__builtin_amdgcn_permlane32_swap)
        uint2v rx = __builtin_amdgcn_permlane32_swap(__float_as_uint(z.x), __float_as_uint(z.x), false, false);
        uint2v ry = __builtin_amdgcn_permlane32_swap(__float_as_uint(z.y), __float_as_uint(z.y), false, false);
        return { make_float2(__uint_as_float(rx[0]), __uint_as_float(ry[0])),
                 make_float2(__uint_as_float(rx[1]), __uint_as_float(ry[1])) };
#else
        return { shflxor2(z, 32), z };
#endif
    } else if constexpr (S == 1) {
#if __has_builtin(__builtin_amdgcn_permlane16_swap)
        uint2v rx = __builtin_amdgcn_permlane16_swap(__float_as_uint(z.x), __float_as_uint(z.x), false, false);
        uint2v ry = __builtin_amdgcn_permlane16_swap(__float_as_uint(z.y), __float_as_uint(z.y), false, false);
        return { make_float2(__uint_as_float(rx[0]), __uint_as_float(ry[0])),
                 make_float2(__uint_as_float(rx[1]), __uint_as_float(ry[1])) };
#else
        return { shflxor2(z, 16), z };
#endif
    } else if constexpr (S == 2) {
        return { make_float2(xp8(z.x), xp8(z.y)), z };
    } else if constexpr (S == 3) {
        return { make_float2(xp4(z.x), xp4(z.y)), z };
    } else if constexpr (S == 4) {
        return { dppqp2<0x4E>(z), z };
    } else {
        return { dppqp2<0xB1>(z), z };
    }
}

template<int S>
__device__ __forceinline__ void stage2(float2* zA, float2* zB, float sg, float2 w){
    const float2 sgv = make_float2(sg, sg);
    #pragma unroll
    for (int r = 0; r < 8; ++r) {
        f2pair a = part<S>(zA[r]);
        f2pair b = part<S>(zB[r]);
        zA[r] = pk_cmul(pk_fma_s(a.Q, sgv, a.P), w);
        zB[r] = pk_cmul(pk_fma_s(b.Q, sgv, b.P), w);
    }
}

// ---- DPP wave scan/reduction (VALU pipe). Inclusive prefix at every lane;
// lane 63 = total. (row_shr 1/2/4/8 + row_bcast15(0xa) + row_bcast31(0xc)) ----
__device__ __forceinline__ float dpp_sum63(float x){
    int v;
    v = __builtin_amdgcn_update_dpp(0, __float_as_int(x), 0x111, 0xf, 0xf, true); x += __int_as_float(v);
    v = __builtin_amdgcn_update_dpp(0, __float_as_int(x), 0x112, 0xf, 0xf, true); x += __int_as_float(v);
    v = __builtin_amdgcn_update_dpp(0, __float_as_int(x), 0x114, 0xf, 0xf, true); x += __int_as_float(v);
    v = __builtin_amdgcn_update_dpp(0, __float_as_int(x), 0x118, 0xf, 0xf, true); x += __int_as_float(v);
    v = __builtin_amdgcn_update_dpp(0, __float_as_int(x), 0x142, 0xa, 0xf, true); x += __int_as_float(v);
    v = __builtin_amdgcn_update_dpp(0, __float_as_int(x), 0x143, 0xc, 0xf, true); x += __int_as_float(v);
    return x;
}
__device__ __forceinline__ float dpp_max63(float x){   // operands >= 0
    int v;
    v = __builtin_amdgcn_update_dpp(0, __float_as_int(x), 0x111, 0xf, 0xf, true); x = fmaxf(x, __int_as_float(v));
    v = __builtin_amdgcn_update_dpp(0, __float_as_int(x), 0x112, 0xf, 0xf, true); x = fmaxf(x, __int_as_float(v));
    v = __builtin_amdgcn_update_dpp(0, __float_as_int(x), 0x114, 0xf, 0xf, true); x = fmaxf(x, __int_as_float(v));
    v = __builtin_amdgcn_update_dpp(0, __float_as_int(x), 0x118, 0xf, 0xf, true); x = fmaxf(x, __int_as_float(v));
    v = __builtin_amdgcn_update_dpp(0, __float_as_int(x), 0x142, 0xa, 0xf, true); x = fmaxf(x, __int_as_float(v));
    v = __builtin_amdgcn_update_dpp(0, __float_as_int(x), 0x143, 0xc, 0xf, true); x = fmaxf(x, __int_as_float(v));
    return x;
}
__device__ __forceinline__ unsigned dpp_umax63(unsigned x){
    int v; unsigned y;
    v = __builtin_amdgcn_update_dpp(0, (int)x, 0x111, 0xf, 0xf, true); y = (unsigned)v; x = x > y ? x : y;
    v = __builtin_amdgcn_update_dpp(0, (int)x, 0x112, 0xf, 0xf, true); y = (unsigned)v; x = x > y ? x : y;
    v = __builtin_amdgcn_update_dpp(0, (int)x, 0x114, 0xf, 0xf, true); y = (unsigned)v; x = x > y ? x : y;
    v = __builtin_amdgcn_update_dpp(0, (int)x, 0x118, 0xf, 0xf, true); y = (unsigned)v; x = x > y ? x : y;
    v = __builtin_amdgcn_update_dpp(0, (int)x, 0x142, 0xa, 0xf, true); y = (unsigned)v; x = x > y ? x : y;
    v = __builtin_amdgcn_update_dpp(0, (int)x, 0x143, 0xc, 0xf, true); y = (unsigned)v; x = x > y ? x : y;
    return x;
}
__device__ __forceinline__ float bcast63f(float x){
    return __int_as_float(__builtin_amdgcn_readlane(__float_as_int(x), 63));
}
__device__ __forceinline__ unsigned bcast63u(unsigned x){
    return (unsigned)__builtin_amdgcn_readlane((int)x, 63);
}

// exp(-i*pi*r/512), r = 0..7 (compile-time literals after unroll)
__device__ __forceinline__ float2 rotc(int r){
    const float C[8] = {1.0f, 0.99998117528f, 0.99992470184f, 0.99983058180f,
                        0.99969881870f, 0.99952941750f, 0.99932238459f, 0.99907772775f};
    const float S[8] = {0.0f, 0.00613588465f, 0.01227153829f, 0.01840672991f,
                        0.02454122852f, 0.03067480318f, 0.03680722294f, 0.04293825693f};
    return make_float2(C[r], -S[r]);
}

__device__ __forceinline__ float psd_combine(float2 z, float2 zr, float2 uw){
    float Ex = 0.5f * (z.x + zr.x);
    float Ey = 0.5f * (z.y - zr.y);
    float Ox = 0.5f * (z.y + zr.y);
    float Oy = -0.5f * (z.x - zr.x);
    float Xx = Ex + uw.x * Ox - uw.y * Oy;
    float Xy = Ey + uw.x * Oy + uw.y * Ox;
    return Xx * Xx + Xy * Xy;
}

// 8-point DIT FFT in registers (packed adds), natural-order output
__device__ __forceinline__ void fft8(float2* z){
    float2 c0 = pk_add(z[0], z[4]), c1 = pk_sub(z[0], z[4]);
    float2 c2 = pk_add(z[2], z[6]), c3 = pk_sub(z[2], z[6]);
    float2 c4 = pk_add(z[1], z[5]), c5 = pk_sub(z[1], z[5]);
    float2 c6 = pk_add(z[3], z[7]), c7 = pk_sub(z[3], z[7]);
    float2 mi3 = make_float2(c3.y, -c3.x);
    float2 mi7 = make_float2(c7.y, -c7.x);
    float2 d0 = pk_add(c0, c2), d2 = pk_sub(c0, c2);
    float2 d1 = pk_add(c1, mi3), d3 = pk_sub(c1, mi3);
    float2 d4 = pk_add(c4, c6), d6 = pk_sub(c4, c6);
    float2 d5 = pk_add(c5, mi7), d7 = pk_sub(c5, mi7);
    const float S2 = 0.70710678118654752f;
    float2 w1d5 = make_float2(S2 * (d5.x + d5.y), S2 * (d5.y - d5.x));
    float2 mid6 = make_float2(d6.y, -d6.x);
    float2 w3d7 = make_float2(S2 * (d7.y - d7.x), -S2 * (d7.x + d7.y));
    z[0] = pk_add(d0, d4);  z[4] = pk_sub(d0, d4);
    z[1] = pk_add(d1, w1d5); z[5] = pk_sub(d1, w1d5);
    z[2] = pk_add(d2, mid6); z[6] = pk_sub(d2, mid6);
    z[3] = pk_add(d3, w3d7); z[7] = pk_sub(d3, w3d7);
}

// LDS staging index swizzle (involution): bits[2:0] ^= bits[8:6]
__device__ __forceinline__ int swz(int idx){ return idx ^ ((idx >> 6) & 7); }

// ---------------- Fused kernel: R14's k1 + last-block-done k2 finale ----------------
// k1 body = EXACT R12/R14 (45.2us validated). After the flush, each block
// fences + increments a counter; the last block runs the R13/R14-validated
// DPP-scan finale inline, eliminating the 2nd launch (~4-6us gap).
// NOTE: no second __launch_bounds__ arg (R3/R5 spills lesson).
// NOTE: flush = lane-consecutive coalesced atomics (R6), 8-way sliced (R10).
// NOTE: all butterfly stages on VALU pipe (permlane_swap / DPP) — R7/R8 lesson.
__global__ __launch_bounds__(256)
void k1(const float* __restrict__ preds, const int* __restrict__ FsPtr,
        float* __restrict__ gpsd, float* __restrict__ gband, float* __restrict__ gsparse,
        int* __restrict__ gcount, float* __restrict__ out, int B, int npair, int nblk)
{
    __shared__ float wacc[4][NF + 7];   // per-wave PSD partials (swizzled index)
    __shared__ float wscal[8];          // per-wave accB, accS
    __shared__ int   isLast;
    __shared__ float wsum[4];
    __shared__ float a512s;
    __shared__ float red[4];

    const int tid  = threadIdx.x;
    const int lane = tid & 63;
    const int wid  = tid >> 6;
    const int Fs   = *FsPtr;

    // band parameters, fp32 (uniform grid => argmin == rint(target/step);
    // values land far from .5 boundaries: Fs=30 -> 22.76, 102.4, 3.42)
    const float fs2f  = (float)Fs * 0.5f;
    const float stepf = fs2f / (float)(NF - 1);
    const int left  = (int)rintf(0.666666667f / stepf);
    const int right = (int)rintf(3.0f / stepf);
    const float binw = fs2f / (float)NF;
    int delta = (int)rintf(0.1f / binw);
    if (delta < 1) delta = 1;

    const int K  = brev6(lane);
    const int kk = K << 3;
    const float PIF = 3.14159265358979323846f;

    // ---- slim prologue: 1 sincosf, everything else derived ----
    float2 t512;
    { float s, c; sincosf(-2.0f * PIF * (float)lane / 512.0f, &s, &c); t512 = make_float2(c, s); }
    const float2 t2  = pk_cmul(t512, t512);    // t512^2
    const float2 u4  = pk_cmul(t2, t2);        // t512^4 = W128^lane
    const float2 w64 = pk_cmul(u4, u4);        // t512^8 = W64^lane
    const float2 uw0 = shflidx2(u4, K);        // e^{-i*pi*K/64}
    const int p0idx = brev6((64 - K) & 63);

    float2 tw2[8];                       // W_512^{lane*r}, r=1..7
    tw2[1] = t512;
    #pragma unroll
    for (int r = 2; r < 8; ++r) tw2[r] = pk_cmul(tw2[r-1], t512);
    float2 wS[6];                        // hi lanes: -v_s; lo: (1,0)
    {
        float2 v = w64;
        #pragma unroll
        for (int s = 0; s < 6; ++s) {
            const int m = 32 >> s;
            wS[s] = (lane & m) ? make_float2(-v.x, -v.y) : make_float2(1.f, 0.f);
            v = pk_cmul(v, v);
        }
    }

    float baccR[8] = {0.f,0.f,0.f,0.f,0.f,0.f,0.f,0.f};
    float bacc512 = 0.f;
    float accB = 0.f, accS = 0.f;

    const int gw   = blockIdx.x * 4 + wid;
    const int row0base = gw * (2 * npair);

    for (int pp = 0; pp < npair; ++pp) {
        const int rowA = row0base + 2 * pp;
        if (rowA >= B) break;
        const int rowB = rowA + 1;
        const float valB = (rowB < B) ? 1.f : 0.f;
        const int rowBc = (rowB < B) ? rowB : rowA;

        // ---- load both rows (coalesced 8B/lane) ----
        const float2* srcA = (const float2*)(preds + (size_t)rowA * NFFT);
        const float2* srcB = (const float2*)(preds + (size_t)rowBc * NFFT);
        float2 zA[8], zB[8];
        #pragma unroll
        for (int r = 0; r < 8; ++r) { zA[r] = srcA[(r << 6) + lane]; zB[r] = srcB[(r << 6) + lane]; }

        // ---- step 1: 8-point FFT (both rows, packed adds) ----
        fft8(zA);
        fft8(zB);

        // ---- step 2: twiddle W_512^{lane*r} (packed cmul) ----
        #pragma unroll
        for (int r = 1; r < 8; ++r) { zA[r] = pk_cmul(zA[r], tw2[r]); zB[r] = pk_cmul(zB[r], tw2[r]); }

        // ---- step 3: 64-point DIF across lanes, all stages VALU (packed) ----
        stage2<0>(zA, zB, (lane & 32) ? -1.f : 1.f, wS[0]);
        stage2<1>(zA, zB, (lane & 16) ? -1.f : 1.f, wS[1]);
        stage2<2>(zA, zB, (lane &  8) ? -1.f : 1.f, wS[2]);
        stage2<3>(zA, zB, (lane &  4) ? -1.f : 1.f, wS[3]);
        stage2<4>(zA, zB, (lane &  2) ? -1.f : 1.f, wS[4]);
        stage2<5>(zA, zB, (lane &  1) ? -1.f : 1.f, wS[5]);
        // lane holds Z[kk + r] for each row

        float p512A = 0.f, p512B = 0.f;
        if (lane == 0) {
            float qA = zA[0].x - zA[0].y; p512A = qA * qA;
            float qB = zB[0].x - zB[0].y; p512B = qB * qB;
        }

        // ---- real-unpack + PSD (both rows) ----
        float PA[8], PB[8];
        {
            float2 zrA = shflidx2(zA[0], p0idx);
            float2 zrB = shflidx2(zB[0], p0idx);
            PA[0] = psd_combine(zA[0], zrA, uw0);
            PB[0] = psd_combine(zB[0], zrB, uw0);
        }
        #pragma unroll
        for (int r = 1; r < 8; ++r) {
            float2 uwr = pk_cmul(uw0, rotc(r));
            float2 zrA = shflxor2(zA[8 - r], 63);
            float2 zrB = shflxor2(zB[8 - r], 63);
            PA[r] = psd_combine(zA[r], zrA, uwr);
            PB[r] = psd_combine(zB[r], zrB, uwr);
        }

        // ---- stats (both rows, DPP reductions) ----
        float tpA = p512A, ipA = 0.f, mvA = 0.f;
        float tpB = p512B, ipB = 0.f, mvB = 0.f;
        #pragma unroll
        for (int r = 0; r < 8; ++r) {
            const int k = kk + r;
            tpA += PA[r]; tpB += PB[r];
            if (k >= left && k < right) {
                ipA += PA[r]; mvA = fmaxf(mvA, PA[r]);
                ipB += PB[r]; mvB = fmaxf(mvB, PB[r]);
            }
        }
        const float tpSA = dpp_sum63(tpA), tpSB = dpp_sum63(tpB);
        const float ipSA = dpp_sum63(ipA), ipSB = dpp_sum63(ipB);
        const float mxA = bcast63f(dpp_max63(mvA));
        const float mxB = bcast63f(dpp_max63(mvB));

        unsigned candA = 0u, candB = 0u;
        #pragma unroll
        for (int r = 0; r < 8; ++r) {
            const int k = kk + r;
            if (k >= left && k < right) {
                if (PA[r] == mxA) { unsigned c = ~(unsigned)k; candA = candA > c ? candA : c; }
                if (PB[r] == mxB) { unsigned c = ~(unsigned)k; candB = candB > c ? candB : c; }
            }
        }
        const int peakA = (int)(~bcast63u(dpp_umax63(candA)));
        const int peakB = (int)(~bcast63u(dpp_umax63(candB)));
        const int loA = max(left, peakA - delta), hiA = min(right, peakA + delta);
        const int loB = max(left, peakB - delta), hiB = min(right, peakB + delta);
        float nsA = 0.f, nsB = 0.f;
        #pragma unroll
        for (int r = 0; r < 8; ++r) {
            const int k = kk + r;
            if (k >= loA && k < hiA) nsA += PA[r];
            if (k >= loB && k < hiB) nsB += PB[r];
        }
        const float nsSA = dpp_sum63(nsA), nsSB = dpp_sum63(nsB);

        const float eps = 1e-8f * (float)(right - left);
        accB += (tpSA - ipSA) / (1e-8f + tpSA) + valB * ((tpSB - ipSB) / (1e-8f + tpSB));
        accS += (ipSA - nsSA) / (ipSA + eps)   + valB * ((ipSB - nsSB) / (ipSB + eps));

        #pragma unroll
        for (int r = 0; r < 8; ++r) baccR[r] += PA[r] + valB * PB[r];
        bacc512 += p512A + valB * p512B;
    }

    // ---- stage per-wave partials in LDS (non-atomic; swizzled index) ----
    #pragma unroll
    for (int r = 0; r < 8; ++r) wacc[wid][swz(kk + r)] = baccR[r];
    if (lane == 0)  wacc[wid][swz(512)] = bacc512;
    if (lane == 63) { wscal[wid] = accB; wscal[4 + wid] = accS; }
    __syncthreads();

    // ---- block flush: coalesced atomics into this block's slice ----
    {
        const int sl = blockIdx.x & (NSL - 1);
        float* slice = gpsd + sl * SLW;
        const int s0i = swz(tid), s1i = swz(tid + 256);
        float s0 = wacc[0][s0i] + wacc[1][s0i] + wacc[2][s0i] + wacc[3][s0i];
        atomicAdd(&slice[tid], s0);
        float s1 = wacc[0][s1i] + wacc[1][s1i] + wacc[2][s1i] + wacc[3][s1i];
        atomicAdd(&slice[tid + 256], s1);
        if (tid == 0) {
            const int s2i = swz(512);
            atomicAdd(&slice[512], wacc[0][s2i] + wacc[1][s2i] + wacc[2][s2i] + wacc[3][s2i]);
            atomicAdd(&gband[sl],   wscal[0] + wscal[1] + wscal[2] + wscal[3]);
            atomicAdd(&gsparse[sl], wscal[4] + wscal[5] + wscal[6] + wscal[7]);
        }
    }

    // ---- last-block-done: the final block runs the k2 finale inline ----
    __threadfence();
    if (tid == 0) {
        const int prev = atomicAdd(gcount, 1);
        isLast = (prev == nblk - 1) ? 1 : 0;
    }
    __syncthreads();
    if (!isLast) return;
    __threadfence();

    // ---- finale (R13/R14-validated DPP scan) ----
    float e0 = 0.f, e1 = 0.f;
    #pragma unroll
    for (int s = 0; s < NSL; ++s) {
        const float2 v = ((const float2*)(gpsd + s * SLW))[tid];
        e0 += v.x; e1 += v.y;
    }
    if (tid == 0) {
        float v = 0.f;
        #pragma unroll
        for (int s = 0; s < NSL; ++s) v += gpsd[s * SLW + 512];
        a512s = v;
    }

    const float s = e0 + e1;
    const float incl = dpp_sum63(s);          // inclusive prefix within wave
    if (lane == 63) wsum[wid] = incl;
    __syncthreads();

    float wpre = 0.f;
    #pragma unroll
    for (int w = 0; w < 4; ++w) if (w < wid) wpre += wsum[w];
    const float totalS = wsum[0] + wsum[1] + wsum[2] + wsum[3] + a512s;

    const float excl = wpre + incl - s;
    const float c0 = excl + e0;
    const float c1 = excl + e0 + e1;

    const double stp = (double)fs2f / (double)(NF - 1);
    const float inv = 1.f / (1e-8f + totalS);

    auto term = [&](int i, float c) -> float {
        float Q = fminf(fmaxf(c * inv, 0.f), 1.f);
        float P = (float)((double)i * stp) / fs2f;
        P = fminf(fmaxf(P, 0.f), 1.f);
        const float d = P - Q;
        return d * d;
    };

    float vp = term(2 * tid, c0) + term(2 * tid + 1, c1);
    if (tid == 255) vp += term(512, totalS);  // cumsum[512] = total

    const float vps = bcast63f(dpp_sum63(vp));
    if (lane == 0) red[wid] = vps;
    __syncthreads();

    if (tid == 0) {
        float bsum = 0.f, ssum = 0.f;
        #pragma unroll
        for (int sl = 0; sl < NSL; ++sl) { bsum += gband[sl]; ssum += gsparse[sl]; }
        const float var = (red[0] + red[1] + red[2] + red[3]) / (float)NF;
        out[0] = bsum / (float)B + ssum / (float)B + var;
    }
}

extern "C" void kernel_launch(void* const* d_in, const int* in_sizes, int n_in,
                              void* d_out, int out_size, void* d_ws, size_t ws_size,
                              hipStream_t stream)
{
    const float* preds = (const float*)d_in[0];
    const int*   Fs    = (const int*)d_in[1];
    const int B = in_sizes[0] / NFFT;

    float* gpsd    = (float*)d_ws;                 // NSL slices of SLW floats
    float* gband   = gpsd + NSL * SLW;             // NSL scalars
    float* gsparse = gband + NSL;                  // NSL scalars
    int*   gcount  = (int*)(gsparse + NSL);        // completion counter

    (void)hipMemsetAsync(d_ws, 0, (NSL * SLW + 2 * NSL + 1) * sizeof(float), stream);

    const int npair = 2;                       // 4 rows per wave -> 1024 blocks
    const int rowsPerWave = 2 * npair;
    const int nwaves = (B + rowsPerWave - 1) / rowsPerWave;
    const int nblk   = (nwaves + 3) / 4;

    hipLaunchKernelGGL(k1, dim3(nblk), dim3(256), 0, stream,
                       preds, Fs, gpsd, gband, gsparse, gcount, (float*)d_out, B, npair, nblk);
}

// Round 16
// 52.722 us; speedup vs baseline: 2.5389x; 2.5389x over previous
//
#include <hip/hip_runtime.h>
#include <math.h>

#define NFFT 1024
#define NF   513   // NFFT/2 + 1
#define NSL  8     // accumulator slices (contention spread)
#define SLW  520   // PSD slice stride (floats)

typedef unsigned uint2v __attribute__((ext_vector_type(2)));
typedef float f32x2 __attribute__((ext_vector_type(2)));

__device__ __forceinline__ f32x2 tov(float2 a){ f32x2 r; r[0]=a.x; r[1]=a.y; return r; }
__device__ __forceinline__ float2 tof(f32x2 a){ return make_float2(a[0], a[1]); }

// ---- packed fp32 complex helpers (VOP3P) — R11/R12-validated ----
__device__ __forceinline__ float2 pk_cmul(float2 af, float2 bf){
    f32x2 a = tov(af), b = tov(bf), t, d;
    asm("v_pk_mul_f32 %0, %1, %2 op_sel:[0,0] op_sel_hi:[0,1]"
        : "=v"(t) : "v"(a), "v"(b));                       // {ax*bx, ax*by}
    asm("v_pk_fma_f32 %0, %1, %2, %3 op_sel:[1,1,0] op_sel_hi:[1,0,1] neg_lo:[1,0,0]"
        : "=v"(d) : "v"(a), "v"(b), "v"(t));               // {-ay*by+t.lo, ay*bx+t.hi}
    return tof(d);
}
__device__ __forceinline__ float2 pk_add(float2 af, float2 bf){
    f32x2 a = tov(af), b = tov(bf), d;
    asm("v_pk_add_f32 %0, %1, %2" : "=v"(d) : "v"(a), "v"(b));
    return tof(d);
}
__device__ __forceinline__ float2 pk_sub(float2 af, float2 bf){
    f32x2 a = tov(af), b = tov(bf), d;
    asm("v_pk_add_f32 %0, %1, %2 neg_lo:[0,1] neg_hi:[0,1]" : "=v"(d) : "v"(a), "v"(b));
    return tof(d);
}
__device__ __forceinline__ float2 pk_fma_s(float2 af, float2 sf, float2 cf){
    f32x2 a = tov(af), s = tov(sf), c = tov(cf), d;
    asm("v_pk_fma_f32 %0, %1, %2, %3" : "=v"(d) : "v"(a), "v"(s), "v"(c));
    return tof(d);
}

__device__ __forceinline__ float2 shflxor2(float2 v, int m){
    return make_float2(__shfl_xor(v.x, m), __shfl_xor(v.y, m));
}
__device__ __forceinline__ float2 shflidx2(float2 v, int idx){
    return make_float2(__shfl(v.x, idx), __shfl(v.y, idx));
}
__device__ __forceinline__ int brev6(int x){ return (int)(__brev((unsigned)x) >> 26); }

// DPP quad_perm: xor1 = [1,0,3,2] = 0xB1, xor2 = [2,3,0,1] = 0x4E
template<int CTRL>
__device__ __forceinline__ float2 dppqp2(float2 v){
    int x = __builtin_amdgcn_update_dpp(0, __float_as_int(v.x), CTRL, 0xf, 0xf, true);
    int y = __builtin_amdgcn_update_dpp(0, __float_as_int(v.y), CTRL, 0xf, 0xf, true);
    return make_float2(__int_as_float(x), __int_as_float(y));
}

// xor-partner within 16-lane row via two masked DPP shifts (VALU pipe, no DS).
template<int CSHL, int CSHR, int BM_SHL, int BM_SHR>
__device__ __forceinline__ float xorshift(float z){
    int t = __builtin_amdgcn_update_dpp(0, __float_as_int(z), CSHL, 0xF, BM_SHL, true);
    t     = __builtin_amdgcn_update_dpp(t, __float_as_int(z), CSHR, 0xF, BM_SHR, false);
    return __int_as_float(t);
}
__device__ __forceinline__ float xp4(float z){ return xorshift<0x104, 0x114, 0x5, 0xA>(z); }
__device__ __forceinline__ float xp8(float z){ return xorshift<0x108, 0x118, 0x3, 0xC>(z); }

// butterfly input pair (P, Q): inner = P + sg*Q  (validated convention)
struct f2pair { float2 P, Q; };

template<int S>
__device__ __forceinline__ f2pair part(float2 z){
    if constexpr (S == 0) {
#if __has_builtin(__builtin_amdgcn_permlane32_swap)
        uint2v rx = __builtin_amdgcn_permlane32_swap(__float_as_uint(z.x), __float_as_uint(z.x), false, false);
        uint2v ry = __builtin_amdgcn_permlane32_swap(__float_as_uint(z.y), __float_as_uint(z.y), false, false);
        return { make_float2(__uint_as_float(rx[0]), __uint_as_float(ry[0])),
                 make_float2(__uint_as_float(rx[1]), __uint_as_float(ry[1])) };
#else
        return { shflxor2(z, 32), z };
#endif
    } else if constexpr (S == 1) {
#if __has_builtin(__builtin_amdgcn_permlane16_swap)
        uint2v rx = __builtin_amdgcn_permlane16_swap(__float_as_uint(z.x), __float_as_uint(z.x), false, false);
        uint2v ry = __builtin_amdgcn_permlane16_swap(__float_as_uint(z.y), __float_as_uint(z.y), false, false);
        return { make_float2(__uint_as_float(rx[0]), __uint_as_float(ry[0])),
                 make_float2(__uint_as_float(rx[1]), __uint_as_float(ry[1])) };
#else
        return { shflxor2(z, 16), z };
#endif
    } else if constexpr (S == 2) {
        return { make_float2(xp8(z.x), xp8(z.y)), z };
    } else if constexpr (S == 3) {
        return { make_float2(xp4(z.x), xp4(z.y)), z };
    } else if constexpr (S == 4) {
        return { dppqp2<0x4E>(z), z };
    } else {
        return { dppqp2<0xB1>(z), z };
    }
}

template<int S>
__device__ __forceinline__ void stage2(float2* zA, float2* zB, float sg, float2 w){
    const float2 sgv = make_float2(sg, sg);
    #pragma unroll
    for (int r = 0; r < 8; ++r) {
        f2pair a = part<S>(zA[r]);
        f2pair b = part<S>(zB[r]);
        zA[r] = pk_cmul(pk_fma_s(a.Q, sgv, a.P), w);
        zB[r] = pk_cmul(pk_fma_s(b.Q, sgv, b.P), w);
    }
}

// ---- DPP wave scan/reduction (VALU pipe). Inclusive prefix at every lane;
// lane 63 = total. (row_shr 1/2/4/8 + row_bcast15(0xa) + row_bcast31(0xc)) ----
__device__ __forceinline__ float dpp_sum63(float x){
    int v;
    v = __builtin_amdgcn_update_dpp(0, __float_as_int(x), 0x111, 0xf, 0xf, true); x += __int_as_float(v);
    v = __builtin_amdgcn_update_dpp(0, __float_as_int(x), 0x112, 0xf, 0xf, true); x += __int_as_float(v);
    v = __builtin_amdgcn_update_dpp(0, __float_as_int(x), 0x114, 0xf, 0xf, true); x += __int_as_float(v);
    v = __builtin_amdgcn_update_dpp(0, __float_as_int(x), 0x118, 0xf, 0xf, true); x += __int_as_float(v);
    v = __builtin_amdgcn_update_dpp(0, __float_as_int(x), 0x142, 0xa, 0xf, true); x += __int_as_float(v);
    v = __builtin_amdgcn_update_dpp(0, __float_as_int(x), 0x143, 0xc, 0xf, true); x += __int_as_float(v);
    return x;
}
__device__ __forceinline__ float dpp_max63(float x){   // operands >= 0
    int v;
    v = __builtin_amdgcn_update_dpp(0, __float_as_int(x), 0x111, 0xf, 0xf, true); x = fmaxf(x, __int_as_float(v));
    v = __builtin_amdgcn_update_dpp(0, __float_as_int(x), 0x112, 0xf, 0xf, true); x = fmaxf(x, __int_as_float(v));
    v = __builtin_amdgcn_update_dpp(0, __float_as_int(x), 0x114, 0xf, 0xf, true); x = fmaxf(x, __int_as_float(v));
    v = __builtin_amdgcn_update_dpp(0, __float_as_int(x), 0x118, 0xf, 0xf, true); x = fmaxf(x, __int_as_float(v));
    v = __builtin_amdgcn_update_dpp(0, __float_as_int(x), 0x142, 0xa, 0xf, true); x = fmaxf(x, __int_as_float(v));
    v = __builtin_amdgcn_update_dpp(0, __float_as_int(x), 0x143, 0xc, 0xf, true); x = fmaxf(x, __int_as_float(v));
    return x;
}
__device__ __forceinline__ unsigned dpp_umax63(unsigned x){
    int v; unsigned y;
    v = __builtin_amdgcn_update_dpp(0, (int)x, 0x111, 0xf, 0xf, true); y = (unsigned)v; x = x > y ? x : y;
    v = __builtin_amdgcn_update_dpp(0, (int)x, 0x112, 0xf, 0xf, true); y = (unsigned)v; x = x > y ? x : y;
    v = __builtin_amdgcn_update_dpp(0, (int)x, 0x114, 0xf, 0xf, true); y = (unsigned)v; x = x > y ? x : y;
    v = __builtin_amdgcn_update_dpp(0, (int)x, 0x118, 0xf, 0xf, true); y = (unsigned)v; x = x > y ? x : y;
    v = __builtin_amdgcn_update_dpp(0, (int)x, 0x142, 0xa, 0xf, true); y = (unsigned)v; x = x > y ? x : y;
    v = __builtin_amdgcn_update_dpp(0, (int)x, 0x143, 0xc, 0xf, true); y = (unsigned)v; x = x > y ? x : y;
    return x;
}
__device__ __forceinline__ float bcast63f(float x){
    return __int_as_float(__builtin_amdgcn_readlane(__float_as_int(x), 63));
}
__device__ __forceinline__ unsigned bcast63u(unsigned x){
    return (unsigned)__builtin_amdgcn_readlane((int)x, 63);
}

// exp(-i*pi*r/512), r = 0..7 (compile-time literals after unroll)
__device__ __forceinline__ float2 rotc(int r){
    const float C[8] = {1.0f, 0.99998117528f, 0.99992470184f, 0.99983058180f,
                        0.99969881870f, 0.99952941750f, 0.99932238459f, 0.99907772775f};
    const float S[8] = {0.0f, 0.00613588465f, 0.01227153829f, 0.01840672991f,
                        0.02454122852f, 0.03067480318f, 0.03680722294f, 0.04293825693f};
    return make_float2(C[r], -S[r]);
}

__device__ __forceinline__ float psd_combine(float2 z, float2 zr, float2 uw){
    float Ex = 0.5f * (z.x + zr.x);
    float Ey = 0.5f * (z.y - zr.y);
    float Ox = 0.5f * (z.y + zr.y);
    float Oy = -0.5f * (z.x - zr.x);
    float Xx = Ex + uw.x * Ox - uw.y * Oy;
    float Xy = Ey + uw.x * Oy + uw.y * Ox;
    return Xx * Xx + Xy * Xy;
}

// 8-point DIT FFT in registers (packed adds), natural-order output
__device__ __forceinline__ void fft8(float2* z){
    float2 c0 = pk_add(z[0], z[4]), c1 = pk_sub(z[0], z[4]);
    float2 c2 = pk_add(z[2], z[6]), c3 = pk_sub(z[2], z[6]);
    float2 c4 = pk_add(z[1], z[5]), c5 = pk_sub(z[1], z[5]);
    float2 c6 = pk_add(z[3], z[7]), c7 = pk_sub(z[3], z[7]);
    float2 mi3 = make_float2(c3.y, -c3.x);
    float2 mi7 = make_float2(c7.y, -c7.x);
    float2 d0 = pk_add(c0, c2), d2 = pk_sub(c0, c2);
    float2 d1 = pk_add(c1, mi3), d3 = pk_sub(c1, mi3);
    float2 d4 = pk_add(c4, c6), d6 = pk_sub(c4, c6);
    float2 d5 = pk_add(c5, mi7), d7 = pk_sub(c5, mi7);
    const float S2 = 0.70710678118654752f;
    float2 w1d5 = make_float2(S2 * (d5.x + d5.y), S2 * (d5.y - d5.x));
    float2 mid6 = make_float2(d6.y, -d6.x);
    float2 w3d7 = make_float2(S2 * (d7.y - d7.x), -S2 * (d7.x + d7.y));
    z[0] = pk_add(d0, d4);  z[4] = pk_sub(d0, d4);
    z[1] = pk_add(d1, w1d5); z[5] = pk_sub(d1, w1d5);
    z[2] = pk_add(d2, mid6); z[6] = pk_sub(d2, mid6);
    z[3] = pk_add(d3, w3d7); z[7] = pk_sub(d3, w3d7);
}

// LDS staging index swizzle (involution): bits[2:0] ^= bits[8:6]
__device__ __forceinline__ int swz(int idx){ return idx ^ ((idx >> 6) & 7); }

// ---------------- Kernel 1: wave-per-4-rows packed-fp32 register FFT ----------------
// EXACT R12/R14 body (45.2us validated). Two-kernel layout: the R15 last-block
// fusion regressed 3x — per-block device-scope __threadfence() on 8 non-coherent
// XCDs serializes the write drain (~100us at 1024 blocks). Launch gap is cheaper.
// NOTE: no second __launch_bounds__ arg (R3/R5 spills lesson).
// NOTE: flush = lane-consecutive coalesced atomics (R6), 8-way sliced (R10).
// NOTE: all butterfly stages on VALU pipe (permlane_swap / DPP) — R7/R8 lesson.
__global__ __launch_bounds__(256)
void k1(const float* __restrict__ preds, const int* __restrict__ FsPtr,
        float* __restrict__ gpsd, float* __restrict__ gband, float* __restrict__ gsparse,
        int B, int npair)
{
    __shared__ float wacc[4][NF + 7];   // per-wave PSD partials (swizzled index)
    __shared__ float wscal[8];          // per-wave accB, accS

    const int tid  = threadIdx.x;
    const int lane = tid & 63;
    const int wid  = tid >> 6;
    const int Fs   = *FsPtr;

    // band parameters, fp32 (uniform grid => argmin == rint(target/step);
    // values land far from .5 boundaries: Fs=30 -> 22.76, 102.4, 3.42)
    const float fs2f  = (float)Fs * 0.5f;
    const float stepf = fs2f / (float)(NF - 1);
    const int left  = (int)rintf(0.666666667f / stepf);
    const int right = (int)rintf(3.0f / stepf);
    const float binw = fs2f / (float)NF;
    int delta = (int)rintf(0.1f / binw);
    if (delta < 1) delta = 1;

    const int K  = brev6(lane);
    const int kk = K << 3;
    const float PIF = 3.14159265358979323846f;

    // ---- slim prologue: 1 sincosf, everything else derived ----
    float2 t512;
    { float s, c; sincosf(-2.0f * PIF * (float)lane / 512.0f, &s, &c); t512 = make_float2(c, s); }
    const float2 t2  = pk_cmul(t512, t512);    // t512^2
    const float2 u4  = pk_cmul(t2, t2);        // t512^4 = W128^lane
    const float2 w64 = pk_cmul(u4, u4);        // t512^8 = W64^lane
    const float2 uw0 = shflidx2(u4, K);        // e^{-i*pi*K/64}
    const int p0idx = brev6((64 - K) & 63);

    float2 tw2[8];                       // W_512^{lane*r}, r=1..7
    tw2[1] = t512;
    #pragma unroll
    for (int r = 2; r < 8; ++r) tw2[r] = pk_cmul(tw2[r-1], t512);
    float2 wS[6];                        // hi lanes: -v_s; lo: (1,0)
    {
        float2 v = w64;
        #pragma unroll
        for (int s = 0; s < 6; ++s) {
            const int m = 32 >> s;
            wS[s] = (lane & m) ? make_float2(-v.x, -v.y) : make_float2(1.f, 0.f);
            v = pk_cmul(v, v);
        }
    }

    float baccR[8] = {0.f,0.f,0.f,0.f,0.f,0.f,0.f,0.f};
    float bacc512 = 0.f;
    float accB = 0.f, accS = 0.f;

    const int gw   = blockIdx.x * 4 + wid;
    const int row0base = gw * (2 * npair);

    for (int pp = 0; pp < npair; ++pp) {
        const int rowA = row0base + 2 * pp;
        if (rowA >= B) break;
        const int rowB = rowA + 1;
        const float valB = (rowB < B) ? 1.f : 0.f;
        const int rowBc = (rowB < B) ? rowB : rowA;

        // ---- load both rows (coalesced 8B/lane) ----
        const float2* srcA = (const float2*)(preds + (size_t)rowA * NFFT);
        const float2* srcB = (const float2*)(preds + (size_t)rowBc * NFFT);
        float2 zA[8], zB[8];
        #pragma unroll
        for (int r = 0; r < 8; ++r) { zA[r] = srcA[(r << 6) + lane]; zB[r] = srcB[(r << 6) + lane]; }

        // ---- step 1: 8-point FFT (both rows, packed adds) ----
        fft8(zA);
        fft8(zB);

        // ---- step 2: twiddle W_512^{lane*r} (packed cmul) ----
        #pragma unroll
        for (int r = 1; r < 8; ++r) { zA[r] = pk_cmul(zA[r], tw2[r]); zB[r] = pk_cmul(zB[r], tw2[r]); }

        // ---- step 3: 64-point DIF across lanes, all stages VALU (packed) ----
        stage2<0>(zA, zB, (lane & 32) ? -1.f : 1.f, wS[0]);
        stage2<1>(zA, zB, (lane & 16) ? -1.f : 1.f, wS[1]);
        stage2<2>(zA, zB, (lane &  8) ? -1.f : 1.f, wS[2]);
        stage2<3>(zA, zB, (lane &  4) ? -1.f : 1.f, wS[3]);
        stage2<4>(zA, zB, (lane &  2) ? -1.f : 1.f, wS[4]);
        stage2<5>(zA, zB, (lane &  1) ? -1.f : 1.f, wS[5]);
        // lane holds Z[kk + r] for each row

        float p512A = 0.f, p512B = 0.f;
        if (lane == 0) {
            float qA = zA[0].x - zA[0].y; p512A = qA * qA;
            float qB = zB[0].x - zB[0].y; p512B = qB * qB;
        }

        // ---- real-unpack + PSD (both rows) ----
        float PA[8], PB[8];
        {
            float2 zrA = shflidx2(zA[0], p0idx);
            float2 zrB = shflidx2(zB[0], p0idx);
            PA[0] = psd_combine(zA[0], zrA, uw0);
            PB[0] = psd_combine(zB[0], zrB, uw0);
        }
        #pragma unroll
        for (int r = 1; r < 8; ++r) {
            float2 uwr = pk_cmul(uw0, rotc(r));
            float2 zrA = shflxor2(zA[8 - r], 63);
            float2 zrB = shflxor2(zB[8 - r], 63);
            PA[r] = psd_combine(zA[r], zrA, uwr);
            PB[r] = psd_combine(zB[r], zrB, uwr);
        }

        // ---- stats (both rows, DPP reductions) ----
        float tpA = p512A, ipA = 0.f, mvA = 0.f;
        float tpB = p512B, ipB = 0.f, mvB = 0.f;
        #pragma unroll
        for (int r = 0; r < 8; ++r) {
            const int k = kk + r;
            tpA += PA[r]; tpB += PB[r];
            if (k >= left && k < right) {
                ipA += PA[r]; mvA = fmaxf(mvA, PA[r]);
                ipB += PB[r]; mvB = fmaxf(mvB, PB[r]);
            }
        }
        const float tpSA = dpp_sum63(tpA), tpSB = dpp_sum63(tpB);
        const float ipSA = dpp_sum63(ipA), ipSB = dpp_sum63(ipB);
        const float mxA = bcast63f(dpp_max63(mvA));
        const float mxB = bcast63f(dpp_max63(mvB));

        unsigned candA = 0u, candB = 0u;
        #pragma unroll
        for (int r = 0; r < 8; ++r) {
            const int k = kk + r;
            if (k >= left && k < right) {
                if (PA[r] == mxA) { unsigned c = ~(unsigned)k; candA = candA > c ? candA : c; }
                if (PB[r] == mxB) { unsigned c = ~(unsigned)k; candB = candB > c ? candB : c; }
            }
        }
        const int peakA = (int)(~bcast63u(dpp_umax63(candA)));
        const int peakB = (int)(~bcast63u(dpp_umax63(candB)));
        const int loA = max(left, peakA - delta), hiA = min(right, peakA + delta);
        const int loB = max(left, peakB - delta), hiB = min(right, peakB + delta);
        float nsA = 0.f, nsB = 0.f;
        #pragma unroll
        for (int r = 0; r < 8; ++r) {
            const int k = kk + r;
            if (k >= loA && k < hiA) nsA += PA[r];
            if (k >= loB && k < hiB) nsB += PB[r];
        }
        const float nsSA = dpp_sum63(nsA), nsSB = dpp_sum63(nsB);

        const float eps = 1e-8f * (float)(right - left);
        accB += (tpSA - ipSA) / (1e-8f + tpSA) + valB * ((tpSB - ipSB) / (1e-8f + tpSB));
        accS += (ipSA - nsSA) / (ipSA + eps)   + valB * ((ipSB - nsSB) / (ipSB + eps));

        #pragma unroll
        for (int r = 0; r < 8; ++r) baccR[r] += PA[r] + valB * PB[r];
        bacc512 += p512A + valB * p512B;
    }

    // ---- stage per-wave partials in LDS (non-atomic; swizzled index) ----
    #pragma unroll
    for (int r = 0; r < 8; ++r) wacc[wid][swz(kk + r)] = baccR[r];
    if (lane == 0)  wacc[wid][swz(512)] = bacc512;
    if (lane == 63) { wscal[wid] = accB; wscal[4 + wid] = accS; }
    __syncthreads();

    // ---- block flush: coalesced atomics into this block's slice ----
    {
        const int sl = blockIdx.x & (NSL - 1);
        float* slice = gpsd + sl * SLW;
        const int s0i = swz(tid), s1i = swz(tid + 256);
        float s0 = wacc[0][s0i] + wacc[1][s0i] + wacc[2][s0i] + wacc[3][s0i];
        atomicAdd(&slice[tid], s0);
        float s1 = wacc[0][s1i] + wacc[1][s1i] + wacc[2][s1i] + wacc[3][s1i];
        atomicAdd(&slice[tid + 256], s1);
        if (tid == 0) {
            const int s2i = swz(512);
            atomicAdd(&slice[512], wacc[0][s2i] + wacc[1][s2i] + wacc[2][s2i] + wacc[3][s2i]);
            atomicAdd(&gband[sl],   wscal[0] + wscal[1] + wscal[2] + wscal[3]);
            atomicAdd(&gsparse[sl], wscal[4] + wscal[5] + wscal[6] + wscal[7]);
        }
    }
}

// ---------------- Kernel 2: variance loss + final combine (DPP scan, R13-validated) ----------------
__global__ __launch_bounds__(256)
void k2(const float* __restrict__ gpsd, const float* __restrict__ gband,
        const float* __restrict__ gsparse, const int* __restrict__ FsPtr,
        float* __restrict__ out, int B)
{
    __shared__ float wsum[4];
    __shared__ float a512s;
    __shared__ float red[4];

    const int tid  = threadIdx.x;
    const int lane = tid & 63;
    const int wid  = tid >> 6;
    const int Fs   = *FsPtr;

    // raw per-element sums over the NSL slices (coalesced float2 loads)
    float e0 = 0.f, e1 = 0.f;
    #pragma unroll
    for (int s = 0; s < NSL; ++s) {
        const float2 v = ((const float2*)(gpsd + s * SLW))[tid];
        e0 += v.x; e1 += v.y;
    }
    if (tid == 0) {
        float v = 0.f;
        #pragma unroll
        for (int s = 0; s < NSL; ++s) v += gpsd[s * SLW + 512];
        a512s = v;
    }

    const float s = e0 + e1;
    const float incl = dpp_sum63(s);          // inclusive prefix within wave
    if (lane == 63) wsum[wid] = incl;
    __syncthreads();

    float wpre = 0.f;
    #pragma unroll
    for (int w = 0; w < 4; ++w) if (w < wid) wpre += wsum[w];
    const float totalS = wsum[0] + wsum[1] + wsum[2] + wsum[3] + a512s;

    const float excl = wpre + incl - s;
    const float c0 = excl + e0;
    const float c1 = excl + e0 + e1;

    const float fs2f = (float)Fs * 0.5f;
    const double stp = (double)fs2f / (double)(NF - 1);
    const float inv = 1.f / (1e-8f + totalS);

    auto term = [&](int i, float c) -> float {
        float Q = fminf(fmaxf(c * inv, 0.f), 1.f);
        float P = (float)((double)i * stp) / fs2f;
        P = fminf(fmaxf(P, 0.f), 1.f);
        const float d = P - Q;
        return d * d;
    };

    float vp = term(2 * tid, c0) + term(2 * tid + 1, c1);
    if (tid == 255) vp += term(512, totalS);  // cumsum[512] = total

    const float vps = bcast63f(dpp_sum63(vp));
    if (lane == 0) red[wid] = vps;
    __syncthreads();

    if (tid == 0) {
        float bsum = 0.f, ssum = 0.f;
        #pragma unroll
        for (int sl = 0; sl < NSL; ++sl) { bsum += gband[sl]; ssum += gsparse[sl]; }
        const float var = (red[0] + red[1] + red[2] + red[3]) / (float)NF;
        out[0] = bsum / (float)B + ssum / (float)B + var;
    }
}

extern "C" void kernel_launch(void* const* d_in, const int* in_sizes, int n_in,
                              void* d_out, int out_size, void* d_ws, size_t ws_size,
                              hipStream_t stream)
{
    const float* preds = (const float*)d_in[0];
    const int*   Fs    = (const int*)d_in[1];
    const int B = in_sizes[0] / NFFT;

    float* gpsd    = (float*)d_ws;                 // NSL slices of SLW floats
    float* gband   = gpsd + NSL * SLW;             // NSL scalars
    float* gsparse = gband + NSL;                  // NSL scalars

    (void)hipMemsetAsync(d_ws, 0, (NSL * SLW + 2 * NSL) * sizeof(float), stream);

    const int npair = 2;                       // 4 rows per wave -> 1024 blocks
    const int rowsPerWave = 2 * npair;
    const int nwaves = (B + rowsPerWave - 1) / rowsPerWave;
    const int nblk   = (nwaves + 3) / 4;

    hipLaunchKernelGGL(k1, dim3(nblk), dim3(256), 0, stream,
                       preds, Fs, gpsd, gband, gsparse, B, npair);
    hipLaunchKernelGGL(k2, dim3(1), dim3(256), 0, stream,
                       gpsd, gband, gsparse, Fs, (float*)d_out, B);
}